// Round 7
// baseline (4694.887 us; speedup 1.0000x reference)
//
#include <hip/hip_runtime.h>

// BiLSTM-CRF, f32-faithful.
// R7: recur gemv re-geometried. R6 was LDS-issue-bound: 40 ds_read_b128 per
// thread/step (5.9us/step, VALUBusy 17.6%). Now thread owns R=4 rows x K=16
// k-slice: all 64 weights in 32 NAMED f32x2 registers (no LDS weights), h
// reads drop to 8 ds_read_b128/thread/step (each h vector feeds 4 rows),
// 16-lane DPP reduce. Sync/group/barriers/parity: byte-identical to R6's
// proven agent-atomic protocol (cross-XCD plain-store visibility is
// impossible; R5 confirmed: dirty remote L2 + cached stale line).

#define SLEN 512
#define NTAG 9
#define NEGV -10000.0f

typedef float f32x2 __attribute__((ext_vector_type(2)));
typedef float f32x4 __attribute__((ext_vector_type(4)));

__device__ __forceinline__ float qsum(float v){
  int t = __builtin_amdgcn_update_dpp(0, __float_as_int(v), 0xB1, 0xF, 0xF, false); // [1,0,3,2]
  v += __int_as_float(t);
  t = __builtin_amdgcn_update_dpp(0, __float_as_int(v), 0x4E, 0xF, 0xF, false);     // [2,3,0,1]
  return v + __int_as_float(t);
}
__device__ __forceinline__ float rsum16(float v){
  v = qsum(v);
  int t = __builtin_amdgcn_update_dpp(0, __float_as_int(v), 0x124, 0xF, 0xF, false); // row_ror:4
  v += __int_as_float(t);
  t = __builtin_amdgcn_update_dpp(0, __float_as_int(v), 0x128, 0xF, 0xF, false);     // row_ror:8
  return v + __int_as_float(t);
}

// dual-batch packed FMA: S.lo += W.lo*h[k0,b0]; S.hi += W.lo*h[k0,b1];
//                        S.lo += W.hi*h[k1,b0]; S.hi += W.hi*h[k1,b1]
#define MAC2(S, WP, HV) { \
  f32x2 _h01{(HV).x,(HV).y}, _h23{(HV).z,(HV).w}; \
  asm("v_pk_fma_f32 %0, %1, %2, %0 op_sel:[0,0,0] op_sel_hi:[0,1,1]" : "+v"(S) : "v"(WP), "v"(_h01)); \
  asm("v_pk_fma_f32 %0, %1, %2, %0 op_sel:[1,0,0] op_sel_hi:[1,1,1]" : "+v"(S) : "v"(WP), "v"(_h23)); }

// 16 NAMED f32x2 pairs = 32 f32 (xproj keeps R6 geometry)
struct WReg { f32x2 a0,a1,a2,a3,a4,a5,a6,a7,a8,a9,a10,a11,a12,a13,a14,a15; };

__device__ __forceinline__ WReg load_wreg(const f32x4* __restrict__ wp, int t){
  WReg r; f32x4 v;
  v = wp[0*1024+t]; r.a0  = f32x2{v.x,v.y}; r.a1  = f32x2{v.z,v.w};
  v = wp[1*1024+t]; r.a2  = f32x2{v.x,v.y}; r.a3  = f32x2{v.z,v.w};
  v = wp[2*1024+t]; r.a4  = f32x2{v.x,v.y}; r.a5  = f32x2{v.z,v.w};
  v = wp[3*1024+t]; r.a6  = f32x2{v.x,v.y}; r.a7  = f32x2{v.z,v.w};
  v = wp[4*1024+t]; r.a8  = f32x2{v.x,v.y}; r.a9  = f32x2{v.z,v.w};
  v = wp[5*1024+t]; r.a10 = f32x2{v.x,v.y}; r.a11 = f32x2{v.z,v.w};
  v = wp[6*1024+t]; r.a12 = f32x2{v.x,v.y}; r.a13 = f32x2{v.z,v.w};
  v = wp[7*1024+t]; r.a14 = f32x2{v.x,v.y}; r.a15 = f32x2{v.z,v.w};
  return r;
}
__device__ __forceinline__ f32x2 gemv_step(const WReg &w, const f32x4* lw, int t,
                                           const float* hb){
  f32x2 s{0.f,0.f};
  f32x4 h;
  h = *(const f32x4*)(hb+ 0); MAC2(s, w.a0,  h);
  h = *(const f32x4*)(hb+ 4); MAC2(s, w.a1,  h);
  h = *(const f32x4*)(hb+ 8); MAC2(s, w.a2,  h);
  h = *(const f32x4*)(hb+12); MAC2(s, w.a3,  h);
  h = *(const f32x4*)(hb+16); MAC2(s, w.a4,  h);
  h = *(const f32x4*)(hb+20); MAC2(s, w.a5,  h);
  h = *(const f32x4*)(hb+24); MAC2(s, w.a6,  h);
  h = *(const f32x4*)(hb+28); MAC2(s, w.a7,  h);
  h = *(const f32x4*)(hb+32); MAC2(s, w.a8,  h);
  h = *(const f32x4*)(hb+36); MAC2(s, w.a9,  h);
  h = *(const f32x4*)(hb+40); MAC2(s, w.a10, h);
  h = *(const f32x4*)(hb+44); MAC2(s, w.a11, h);
  h = *(const f32x4*)(hb+48); MAC2(s, w.a12, h);
  h = *(const f32x4*)(hb+52); MAC2(s, w.a13, h);
  h = *(const f32x4*)(hb+56); MAC2(s, w.a14, h);
  h = *(const f32x4*)(hb+60); MAC2(s, w.a15, h);
  #pragma unroll
  for (int q=0; q<8; q++){
    f32x4 wc = lw[q*1024 + t];
    f32x4 hA = *(const f32x4*)(hb + 64 + 8*q);
    f32x4 hB = *(const f32x4*)(hb + 68 + 8*q);
    f32x2 w1{wc.x,wc.y}; MAC2(s, w1, hA);
    f32x2 w2{wc.z,wc.w}; MAC2(s, w2, hB);
  }
  return s;
}

// role 0 (Wih, xproj — R6 layout):
//   wS[(((d*4+g)*2+m)*8+q)*4096 + t*4 + e] = Wih_d[g*256+(t>>2)][(t&3)*64+m*32+q*4+e]
// role 1 (Whh, recur — R7 layout, inst = rr*4+kq):
//   wS[(((2+d)*4+g)*16 + inst)*4096 + t*4 + e] = Whh_d[g*256+(t>>4)*4+rr][(t&15)*16+kq*4+e]
__global__ void prep_k(const float* __restrict__ wihf, const float* __restrict__ whhf,
                       const float* __restrict__ wihr, const float* __restrict__ whhr,
                       float* __restrict__ wS){
  for (int i = blockIdx.x*blockDim.x + threadIdx.x; i < (1<<20); i += gridDim.x*blockDim.x){
    int e=i&3, t=(i>>2)&1023, inst=(i>>12)&15, g=(i>>16)&3, d=(i>>18)&1, role=(i>>19)&1;
    int row, k;
    const float* s;
    if (role == 0){
      int m = inst>>3, q = inst&7;
      row = g*256 + (t>>2);
      k   = (t&3)*64 + m*32 + q*4 + e;
      s = d ? wihr : wihf;
    } else {
      int rr = inst>>2, kq = inst&3;
      row = g*256 + (t>>4)*4 + rr;
      k   = (t&15)*16 + kq*4 + e;
      s = d ? whhr : whhf;
    }
    wS[i] = s[row*256 + k];
  }
}

// xproj: unchanged from R6 (block (d,g,bp): gate-g pre-activations + bias).
__global__ __launch_bounds__(1024, 4) void xproj_k(
    int c0, int Sc,
    const int* __restrict__ ids, const float* __restrict__ embed,
    const float* __restrict__ wS,
    const float* __restrict__ bias_f, const float* __restrict__ bias_r,
    float* __restrict__ xg, long xg_par_str)
{
  __shared__ f32x4 lw4[8192];
  __shared__ __align__(16) float xl2[2][544];
  __shared__ int ids_l[1024];
  const int t = threadIdx.x;
  const int bid = blockIdx.x;
  const int bp = bid & 31, g = (bid>>5)&3, d = bid>>7;
  const int j = t>>2, c = t&3;

  const f32x4* wp = (const f32x4*)(wS + ((long)(d*4+g)*2)*32768);
  WReg w = load_wreg(wp, t);
  #pragma unroll
  for (int q=0; q<8; q++) lw4[q*1024+t] = wp[(8+q)*1024 + t];

  const float bb = (d ? bias_r : bias_f)[g*256 + j];
  for (int i=t; i<2*Sc; i+=1024){
    int b = (i>=Sc) ? 1 : 0, sp = i - b*Sc;
    int sg = d ? (SLEN-1-(c0*Sc+sp)) : (c0*Sc+sp);
    ids_l[i] = ids[(bp*2+b)*SLEN + sg];
  }
  __syncthreads();
  const int bl = t&1, kk = t>>1;
  if (t < 128){
    f32x4 v = ((const f32x4*)embed)[(long)ids_l[bl*Sc]*64 + kk];
    #pragma unroll
    for (int ii=0; ii<4; ii++){
      int k = kk*4+ii;
      xl2[0][(k>>6)*132 + (k&63)*2 + bl] = v[ii];
    }
  }
  __syncthreads();
  float* xgb = xg + (long)(c0&1)*xg_par_str;
  for (int sp=0; sp<Sc; sp++){
    f32x4 pfv;
    const bool hpf = (sp+1 < Sc) && (t < 128);
    if (hpf) pfv = ((const f32x4*)embed)[(long)ids_l[bl*Sc + sp+1]*64 + kk];
    f32x2 s = gemv_step(w, lw4, t, &xl2[sp&1][c*132]);
    float s0 = qsum(s.x), s1 = qsum(s.y);
    if (c < 2){
      float val = (c ? s1 : s0) + bb;
      xgb[((long)(d*Sc+sp)*64 + (bp*2+c))*1024 + g*256 + j] = val;
    }
    if (hpf){
      #pragma unroll
      for (int ii=0; ii<4; ii++){
        int k = kk*4+ii;
        xl2[(sp+1)&1][(k>>6)*132 + (k&63)*2 + bl] = pfv[ii];
      }
    }
    __syncthreads();
  }
}

// recur: thread (rg=t>>4, ks=t&15) owns rows rg*4..+3, k-slice ks*16..+15.
// h LDS: hl2[ks*36 + kk*2 + b] (stride 36 spreads banks, <=4-way).
#define LDW(rr,kq,A,B) { f32x4 v = wp[((rr)*4+(kq))*1024 + t]; A = f32x2{v.x,v.y}; B = f32x2{v.z,v.w}; }
#define MROW(S,W0,W1,W2,W3,W4,W5,W6,W7) \
  MAC2(S,W0,h0) MAC2(S,W1,h1) MAC2(S,W2,h2) MAC2(S,W3,h3) \
  MAC2(S,W4,h4) MAC2(S,W5,h5) MAC2(S,W6,h6) MAC2(S,W7,h7)

__global__ __launch_bounds__(1024, 4) void recur_k(
    int c0, int Sc,
    const int* __restrict__ ids,
    const float* __restrict__ wS,
    const float* __restrict__ xg, long xg_par_str,
    float* __restrict__ hs,
    float* __restrict__ st_h, float* __restrict__ st_c,
    float* __restrict__ send, int* __restrict__ flags)
{
  __shared__ __align__(16) float hl2[576];
  __shared__ int ml[1024];
  const int t = threadIdx.x;
  const int bid = blockIdx.x;
  const int g = (bid>>3)&3;
  const int grp = (bid&7) | ((bid>>5)<<3);
  const int d = grp>>5, bp = grp&31;
  const int rg = t>>4, ks = t&15;

  const f32x4* wp = (const f32x4*)(wS + ((long)((2+d)*4+g)*16)*4096);
  f32x2 w00,w01,w02,w03,w04,w05,w06,w07;
  f32x2 w10,w11,w12,w13,w14,w15,w16,w17;
  f32x2 w20,w21,w22,w23,w24,w25,w26,w27;
  f32x2 w30,w31,w32,w33,w34,w35,w36,w37;
  LDW(0,0,w00,w01) LDW(0,1,w02,w03) LDW(0,2,w04,w05) LDW(0,3,w06,w07)
  LDW(1,0,w10,w11) LDW(1,1,w12,w13) LDW(1,2,w14,w15) LDW(1,3,w16,w17)
  LDW(2,0,w20,w21) LDW(2,1,w22,w23) LDW(2,2,w24,w25) LDW(2,3,w26,w27)
  LDW(3,0,w30,w31) LDW(3,1,w32,w33) LDW(3,2,w34,w35) LDW(3,3,w36,w37)

  for (int i=t; i<2*Sc; i+=1024){
    int b = (i>=Sc) ? 1 : 0, sp = i - b*Sc;
    int sg = d ? (SLEN-1-(c0*Sc+sp)) : (c0*Sc+sp);
    ml[i] = ids[(bp*2+b)*SLEN + sg];
  }
  float cst = 0.f, hpv = 0.f;
  const int j2 = t&255, b2 = t>>8;               // update mapping (t<512)
  if (t < 512){
    int bg = bp*2 + b2;
    hpv = st_h[(d*64+bg)*256 + j2];
    cst = st_c[(d*64+bg)*256 + j2];
    hl2[(j2>>4)*36 + (j2&15)*2 + b2] = hpv;
  }
  __syncthreads();
  const float* xgb = xg + (long)(c0&1)*xg_par_str;
  const float* hb = hl2 + ks*36;

  for (int sp=0; sp<Sc; sp++){
    const int stepg = c0*Sc + sp;
    const int par = stepg & 1;
    const int target = stepg + 1;
    float x0=0,x1=0,x2=0,x3=0;
    if (t < 512){
      const float* xr = xgb + ((long)(d*Sc+sp)*64 + (bp*2+b2))*1024 + j2;
      x0 = xr[0]; x1 = xr[256]; x2 = xr[512]; x3 = xr[768];
    }
    // ---- gemv: 8 h loads feed 4 rows ----
    f32x4 h0 = *(const f32x4*)(hb+ 0), h1 = *(const f32x4*)(hb+ 4);
    f32x4 h2 = *(const f32x4*)(hb+ 8), h3 = *(const f32x4*)(hb+12);
    f32x4 h4 = *(const f32x4*)(hb+16), h5 = *(const f32x4*)(hb+20);
    f32x4 h6 = *(const f32x4*)(hb+24), h7 = *(const f32x4*)(hb+28);
    f32x2 s0{0.f,0.f}, s1{0.f,0.f}, s2{0.f,0.f}, s3{0.f,0.f};
    MROW(s0,w00,w01,w02,w03,w04,w05,w06,w07)
    MROW(s1,w10,w11,w12,w13,w14,w15,w16,w17)
    MROW(s2,w20,w21,w22,w23,w24,w25,w26,w27)
    MROW(s3,w30,w31,w32,w33,w34,w35,w36,w37)
    float r0a = rsum16(s0.x), r0b = rsum16(s0.y);
    float r1a = rsum16(s1.x), r1b = rsum16(s1.y);
    float r2a = rsum16(s2.x), r2b = rsum16(s2.y);
    float r3a = rsum16(s3.x), r3b = rsum16(s3.y);
    if (ks == 0){
      float* sb = send + ((long)(par*64+grp)*4 + g)*512 + rg*8;
      union { float f[2]; unsigned long long u; } cv;
      cv.f[0]=r0a; cv.f[1]=r0b;
      __hip_atomic_store((unsigned long long*)(sb+0), cv.u, __ATOMIC_RELAXED, __HIP_MEMORY_SCOPE_AGENT);
      cv.f[0]=r1a; cv.f[1]=r1b;
      __hip_atomic_store((unsigned long long*)(sb+2), cv.u, __ATOMIC_RELAXED, __HIP_MEMORY_SCOPE_AGENT);
      cv.f[0]=r2a; cv.f[1]=r2b;
      __hip_atomic_store((unsigned long long*)(sb+4), cv.u, __ATOMIC_RELAXED, __HIP_MEMORY_SCOPE_AGENT);
      cv.f[0]=r3a; cv.f[1]=r3b;
      __hip_atomic_store((unsigned long long*)(sb+6), cv.u, __ATOMIC_RELAXED, __HIP_MEMORY_SCOPE_AGENT);
    }
    __syncthreads();                             // vmcnt drained: sends visible
    if (t == 0)
      __hip_atomic_store(&flags[grp*4+g], target, __ATOMIC_RELEASE, __HIP_MEMORY_SCOPE_AGENT);
    if (t < 3){                                  // same-lane-stream: store precedes poll
      int src = grp*4 + ((g+1+t)&3);
      int cnt = 0;
      while (__hip_atomic_load(&flags[src], __ATOMIC_ACQUIRE, __HIP_MEMORY_SCOPE_AGENT) < target){
        if (++cnt > (1<<16)) break;
      }
    }
    __syncthreads();                             // all 4 gates visible
    if (t < 512){
      const float* rb = send + (long)(par*64+grp)*4*512 + j2*2 + b2;
      float g0 = __hip_atomic_load(rb,      __ATOMIC_RELAXED, __HIP_MEMORY_SCOPE_AGENT);
      float g1 = __hip_atomic_load(rb+512,  __ATOMIC_RELAXED, __HIP_MEMORY_SCOPE_AGENT);
      float g2 = __hip_atomic_load(rb+1024, __ATOMIC_RELAXED, __HIP_MEMORY_SCOPE_AGENT);
      float g3 = __hip_atomic_load(rb+1536, __ATOMIC_RELAXED, __HIP_MEMORY_SCOPE_AGENT);
      float pi = g0 + x0, pf = g1 + x1, pg = g2 + x2, po = g3 + x3;
      float ii = 1.f/(1.f+expf(-pi)), ff = 1.f/(1.f+expf(-pf));
      float gv = tanhf(pg),           oo = 1.f/(1.f+expf(-po));
      float cn = ff*cst + ii*gv;
      float hn = oo*tanhf(cn);
      if (ml[b2*Sc+sp] != 0){ cst = cn; hpv = hn; }   // freeze on masked steps
      hl2[(j2>>4)*36 + (j2&15)*2 + b2] = hpv;
      if (g == 0){
        int sg = d ? (SLEN-1-stepg) : stepg;
        hs[((long)sg*64 + (bp*2+b2))*512 + d*256 + j2] = hpv;
      }
    }
    __syncthreads();                             // hl2 ready for next gemv
  }
  if (t < 512){
    int bg = bp*2 + b2;
    st_h[(d*64+bg)*256 + j2] = hpv;
    st_c[(d*64+bg)*256 + j2] = cst;
  }
}

__global__ __launch_bounds__(576) void feats_k(
    const float* __restrict__ hs, const float* __restrict__ wout,
    float* __restrict__ feats)
{
  __shared__ __align__(16) float hlds[64*512];
  __shared__ __align__(16) float wl[NTAG*512];
  const int s = blockIdx.x, t = threadIdx.x;
  for (int i = t; i < 64*512/4; i += 576)
    ((f32x4*)hlds)[i] = ((const f32x4*)(hs + (long)s*64*512))[i];
  for (int i = t; i < NTAG*512/4; i += 576)
    ((f32x4*)wl)[i] = ((const f32x4*)wout)[i];
  __syncthreads();
  int b = t / 9, tag = t - b*9;
  float acc = 0.f;
  const float* hb = hlds + b*512;
  const float* wb = wl + tag*512;
  for (int k=0; k<512; k+=4){
    f32x4 h4 = *(const f32x4*)(hb+k);
    f32x4 w4 = *(const f32x4*)(wb+k);
    acc += h4.x*w4.x + h4.y*w4.y + h4.z*w4.z + h4.w*w4.w;
  }
  feats[((long)s*64 + b)*9 + tag] = acc;
}

__global__ __launch_bounds__(64) void viterbi_k(
    const int* __restrict__ ids, const float* __restrict__ feats,
    const float* __restrict__ bout, const float* __restrict__ trans,
    int* __restrict__ outp)
{
  __shared__ float fl[SLEN*NTAG + 64];
  __shared__ unsigned char bps[SLEN*NTAG];
  __shared__ unsigned char mk[SLEN];
  const int b = blockIdx.x, lane = threadIdx.x;
  for (int i=lane; i<SLEN; i+=64) mk[i] = (ids[b*SLEN+i] != 0) ? 1 : 0;
  for (int i=lane; i<SLEN*NTAG; i+=64){
    int s = i/9; int t = i - s*9;
    fl[i] = feats[((long)s*64+b)*9 + t] + bout[t];
  }
  fl[SLEN*NTAG + lane] = 0.f;
  __syncthreads();

  float Tc[9], v[9], vown;
  #pragma unroll
  for (int i=0;i<9;i++) Tc[i] = (lane<9)? trans[i*9 + lane] : 0.f;
  #pragma unroll
  for (int i=0;i<9;i++) v[i] = (i==0)?0.f:NEGV;
  vown = (lane==0)?0.f:NEGV;

  for (int s=0;s<SLEN;s++){
    float best = v[0] + Tc[0]; int bi = 0;
    #pragma unroll
    for (int i=1;i<9;i++){
      float sc = v[i] + Tc[i];
      if (sc > best){ best = sc; bi = i; }       // first-max tie-break
    }
    float nv = best + fl[s*9 + lane];
    bool m = mk[s] != 0;
    if (m && lane<9) vown = nv;
    if (lane < 9) bps[s*9+lane] = (unsigned char)bi;
    #pragma unroll
    for (int i=0;i<9;i++) v[i] = __shfl(vown, i);
  }
  if (lane == 0){
    float best = v[0]; int tag = 0;
    #pragma unroll
    for (int i=1;i<9;i++) if (v[i] > best){ best=v[i]; tag=i; }
    outp[b*SLEN + SLEN-1] = tag;
    for (int t=SLEN-1; t>=1; t--){
      int pv = bps[t*9 + tag];
      if (!mk[t]) pv = 0;
      outp[b*SLEN + t-1] = pv;
      tag = pv;
    }
  }
}

extern "C" void kernel_launch(void* const* d_in, const int* in_sizes, int n_in,
                              void* d_out, int out_size, void* d_ws, size_t ws_size,
                              hipStream_t stream){
  (void)in_sizes; (void)n_in; (void)out_size;
  const int*   ids   = (const int*)  d_in[0];
  const float* embed = (const float*)d_in[2];
  const float* Wih_f = (const float*)d_in[3];
  const float* Whh_f = (const float*)d_in[4];
  const float* b_f   = (const float*)d_in[5];
  const float* Wih_r = (const float*)d_in[6];
  const float* Whh_r = (const float*)d_in[7];
  const float* b_r   = (const float*)d_in[8];
  const float* Wout  = (const float*)d_in[9];
  const float* bout  = (const float*)d_in[10];
  const float* trans = (const float*)d_in[11];

  float* fw = (float*)d_ws;
  size_t off = 0;
  float* wS    = fw + off; off += 1048576;     // 4 MB swizzled Wih+Whh
  float* send  = fw + off; off += 262144;      // 1 MB (2 parities)
  float* st_h  = fw + off; off += 32768;
  float* st_c  = fw + off; off += 32768;
  float* hs    = fw + off; off += 16777216;    // 64 MB [512][64][512]
  float* featb = fw + off; off += 294912;      // [512][64][9]
  int*   flags = (int*)(fw + off); off += 256;
  float* xg    = fw + off;
  size_t fixedB = off*4;

  const int cands[7] = {512,256,128,64,32,16,8};
  int Sc = 8;
  for (int ci=0; ci<7; ci++){
    size_t need = fixedB + (size_t)cands[ci]*262144*4;  // xg = 2par*2d*Sc*64*1024 f32
    if (need <= ws_size){ Sc = cands[ci]; break; }
  }
  const long xg_par_str = (long)Sc*131072;
  const int C = SLEN / Sc;

  hipMemsetAsync(flags, 0, 1024, stream);
  hipMemsetAsync(st_h, 0, 2*32768*4, stream);          // st_h + st_c contiguous
  prep_k<<<1024,256,0,stream>>>(Wih_f, Whh_f, Wih_r, Whh_r, wS);
  for (int c0=0; c0<C; c0++){
    xproj_k<<<256,1024,0,stream>>>(c0, Sc, ids, embed, wS, b_f, b_r, xg, xg_par_str);
    recur_k<<<256,1024,0,stream>>>(c0, Sc, ids, wS, xg, xg_par_str, hs, st_h, st_c,
                                   send, flags);
  }
  feats_k<<<512,576,0,stream>>>(hs, Wout, featb);
  viterbi_k<<<64,64,0,stream>>>(ids, featb, bout, trans, (int*)d_out);
}

// Round 8
// 2009.762 us; speedup vs baseline: 2.3360x; 2.3360x over previous
//
#include <hip/hip_runtime.h>

// BiLSTM-CRF, f32-faithful.
// R8: (1) amdgpu_waves_per_eu(4,4) pins the occupancy target so the
// allocator may actually use up to 128 VGPRs (R1..R7: backend heuristic
// capped at 64 and reloaded "resident" weights from L2 every step).
// (2) Tagged-data sync: each sent gate value is one 8B agent atomic
// {f32 val, i32 tag}; consumers poll remote DATA directly (tag>=target
// => valid, atomicity carries the release). One IC RTT/step instead of
// two (flag+data), one barrier removed. Own gate via LDS. send memset'd
// per call (tags must not survive graph replays). (3) Sender lanes ks<4
// store 32B-contiguous quads (agent atomics write through per-sector:
// R7's strided stores cost 4x WRITE amplification).

#define SLEN 512
#define NTAG 9
#define NEGV -10000.0f

typedef float f32x2 __attribute__((ext_vector_type(2)));
typedef float f32x4 __attribute__((ext_vector_type(4)));

__device__ __forceinline__ float qsum(float v){
  int t = __builtin_amdgcn_update_dpp(0, __float_as_int(v), 0xB1, 0xF, 0xF, false); // [1,0,3,2]
  v += __int_as_float(t);
  t = __builtin_amdgcn_update_dpp(0, __float_as_int(v), 0x4E, 0xF, 0xF, false);     // [2,3,0,1]
  return v + __int_as_float(t);
}
__device__ __forceinline__ float rsum16(float v){
  v = qsum(v);
  int t = __builtin_amdgcn_update_dpp(0, __float_as_int(v), 0x124, 0xF, 0xF, false); // row_ror:4
  v += __int_as_float(t);
  t = __builtin_amdgcn_update_dpp(0, __float_as_int(v), 0x128, 0xF, 0xF, false);     // row_ror:8
  return v + __int_as_float(t);
}

// dual-batch packed FMA: S.lo += W.lo*h[k0,b0]; S.hi += W.lo*h[k0,b1];
//                        S.lo += W.hi*h[k1,b0]; S.hi += W.hi*h[k1,b1]
#define MAC2(S, WP, HV) { \
  f32x2 _h01{(HV).x,(HV).y}, _h23{(HV).z,(HV).w}; \
  asm("v_pk_fma_f32 %0, %1, %2, %0 op_sel:[0,0,0] op_sel_hi:[0,1,1]" : "+v"(S) : "v"(WP), "v"(_h01)); \
  asm("v_pk_fma_f32 %0, %1, %2, %0 op_sel:[1,0,0] op_sel_hi:[1,1,1]" : "+v"(S) : "v"(WP), "v"(_h23)); }

// load one wS f32x4 into two named weight pairs
#define LDW(rr,kq,A,B) { f32x4 v = wp[((rr)*4+(kq))*1024 + t]; A = f32x2{v.x,v.y}; B = f32x2{v.z,v.w}; }

#define DECLW \
  f32x2 w00,w01,w02,w03,w04,w05,w06,w07; \
  f32x2 w10,w11,w12,w13,w14,w15,w16,w17; \
  f32x2 w20,w21,w22,w23,w24,w25,w26,w27; \
  f32x2 w30,w31,w32,w33,w34,w35,w36,w37; \
  LDW(0,0,w00,w01) LDW(0,1,w02,w03) LDW(0,2,w04,w05) LDW(0,3,w06,w07) \
  LDW(1,0,w10,w11) LDW(1,1,w12,w13) LDW(1,2,w14,w15) LDW(1,3,w16,w17) \
  LDW(2,0,w20,w21) LDW(2,1,w22,w23) LDW(2,2,w24,w25) LDW(2,3,w26,w27) \
  LDW(3,0,w30,w31) LDW(3,1,w32,w33) LDW(3,2,w34,w35) LDW(3,3,w36,w37)

// chunked gemv: 2 LDS loads + 8 MAC2 per chunk keeps live h-regs at 8
#define GCHUNK(c, WA0,WA1, WB0,WB1, WC0,WC1, WD0,WD1) { \
  f32x4 hA = *(const f32x4*)(hb + (c)*8); \
  f32x4 hB = *(const f32x4*)(hb + (c)*8 + 4); \
  MAC2(s0,WA0,hA) MAC2(s0,WA1,hB) \
  MAC2(s1,WB0,hA) MAC2(s1,WB1,hB) \
  MAC2(s2,WC0,hA) MAC2(s2,WC1,hB) \
  MAC2(s3,WD0,hA) MAC2(s3,WD1,hB) }

#define GEMV4x16 \
  f32x2 s0{0.f,0.f}, s1{0.f,0.f}, s2{0.f,0.f}, s3{0.f,0.f}; \
  GCHUNK(0, w00,w01, w10,w11, w20,w21, w30,w31) \
  GCHUNK(1, w02,w03, w12,w13, w22,w23, w32,w33) \
  GCHUNK(2, w04,w05, w14,w15, w24,w25, w34,w35) \
  GCHUNK(3, w06,w07, w16,w17, w26,w27, w36,w37)

union PK { struct { float v; int tg; } s; unsigned long long u; };

// wS[(((role*2+d)*4+g)*16 + rr*4+kq)*4096 + t*4 + e] =
//   W[g*256 + (t>>4)*4 + rr][(t&15)*16 + kq*4 + e]   role0=Wih, role1=Whh
__global__ void prep_k(const float* __restrict__ wihf, const float* __restrict__ whhf,
                       const float* __restrict__ wihr, const float* __restrict__ whhr,
                       float* __restrict__ wS){
  for (int i = blockIdx.x*blockDim.x + threadIdx.x; i < (1<<20); i += gridDim.x*blockDim.x){
    int e=i&3, t=(i>>2)&1023, inst=(i>>12)&15, g=(i>>16)&3, d=(i>>18)&1, role=(i>>19)&1;
    int rr = inst>>2, kq = inst&3;
    int row = g*256 + (t>>4)*4 + rr;
    int k   = (t&15)*16 + kq*4 + e;
    const float* s = role ? (d? whhr : whhf) : (d? wihr : wihf);
    wS[i] = s[row*256 + k];
  }
}

// xproj: block (d,g,bp): gate-g pre-activations (+bias) for batches
// {2bp,2bp+1}, Sc steps. Thread (rg=t>>4, ks=t&15): rows rg*4..+3, k ks*16..+15.
__global__ __launch_bounds__(1024)
__attribute__((amdgpu_waves_per_eu(4,4)))
void xproj_k(
    int c0, int Sc,
    const int* __restrict__ ids, const float* __restrict__ embed,
    const float* __restrict__ wS,
    const float* __restrict__ bias_f, const float* __restrict__ bias_r,
    float* __restrict__ xg, long xg_par_str)
{
  __shared__ __align__(16) float xl2[2][576];
  __shared__ int ids_l[1024];
  const int t = threadIdx.x;
  const int bid = blockIdx.x;
  const int bp = bid & 31, g = (bid>>5)&3, d = bid>>7;
  const int rg = t>>4, ks = t&15;

  const f32x4* wp = (const f32x4*)(wS + (long)((d*4+g)*16)*4096);
  DECLW
  const float bbr = (d ? bias_r : bias_f)[g*256 + rg*4 + (ks&3)];

  for (int i=t; i<2*Sc; i+=1024){
    int b = (i>=Sc) ? 1 : 0, sp = i - b*Sc;
    int sg = d ? (SLEN-1-(c0*Sc+sp)) : (c0*Sc+sp);
    ids_l[i] = ids[(bp*2+b)*SLEN + sg];
  }
  __syncthreads();
  const int bl = t&1, kk = t>>1;                 // loader mapping (t<128)
  if (t < 128){
    f32x4 v = ((const f32x4*)embed)[(long)ids_l[bl*Sc]*64 + kk];
    #pragma unroll
    for (int ii=0; ii<4; ii++){
      int k = kk*4+ii;
      xl2[0][(k>>4)*36 + (k&15)*2 + bl] = v[ii];
    }
  }
  __syncthreads();
  float* xgb = xg + (long)(c0&1)*xg_par_str;
  const float* hb = xl2[0] + ks*36;              // re-based per parity below
  for (int sp=0; sp<Sc; sp++){
    f32x4 pfv;
    const bool hpf = (sp+1 < Sc) && (t < 128);
    if (hpf) pfv = ((const f32x4*)embed)[(long)ids_l[bl*Sc + sp+1]*64 + kk];
    hb = xl2[sp&1] + ks*36;
    GEMV4x16
    float r0a = rsum16(s0.x), r0b = rsum16(s0.y);
    float r1a = rsum16(s1.x), r1b = rsum16(s1.y);
    float r2a = rsum16(s2.x), r2b = rsum16(s2.y);
    float r3a = rsum16(s3.x), r3b = rsum16(s3.y);
    if (ks < 4){
      float ra = (ks==0)?r0a:(ks==1)?r1a:(ks==2)?r2a:r3a;
      float rb = (ks==0)?r0b:(ks==1)?r1b:(ks==2)?r2b:r3b;
      int j = rg*4 + ks;
      long base = ((long)(d*Sc+sp)*64 + bp*2)*1024 + g*256 + j;
      xgb[base]        = ra + bbr;
      xgb[base + 1024] = rb + bbr;
    }
    if (hpf){
      #pragma unroll
      for (int ii=0; ii<4; ii++){
        int k = kk*4+ii;
        xl2[(sp+1)&1][(k>>4)*36 + (k&15)*2 + bl] = pfv[ii];
      }
    }
    __syncthreads();
  }
}

// recur: blockIdx bits [2:0]=grp_lo, [4:3]=g, [7:5]=grp_hi.
// Tagged-data sync: send[par][grp][g][b][j] = {f32 val, i32 tag} (8B atomic).
__global__ __launch_bounds__(1024)
__attribute__((amdgpu_waves_per_eu(4,4)))
void recur_k(
    int c0, int Sc,
    const int* __restrict__ ids,
    const float* __restrict__ wS,
    const float* __restrict__ xg, long xg_par_str,
    float* __restrict__ hs,
    float* __restrict__ st_h, float* __restrict__ st_c,
    unsigned long long* __restrict__ send)
{
  __shared__ __align__(16) float hl2[576];
  __shared__ float ol[2][256];
  __shared__ int ml[1024];
  const int t = threadIdx.x;
  const int bid = blockIdx.x;
  const int g = (bid>>3)&3;
  const int grp = (bid&7) | ((bid>>5)<<3);
  const int d = grp>>5, bp = grp&31;
  const int rg = t>>4, ks = t&15;

  const f32x4* wp = (const f32x4*)(wS + (long)(((2+d)*4+g)*16)*4096);
  DECLW

  for (int i=t; i<2*Sc; i+=1024){
    int b = (i>=Sc) ? 1 : 0, sp = i - b*Sc;
    int sg = d ? (SLEN-1-(c0*Sc+sp)) : (c0*Sc+sp);
    ml[i] = ids[(bp*2+b)*SLEN + sg];
  }
  float cst = 0.f, hpv = 0.f;
  const int j2 = t&255, b2 = t>>8;               // update mapping (t<512)
  if (t < 512){
    int bg = bp*2 + b2;
    hpv = st_h[(d*64+bg)*256 + j2];
    cst = st_c[(d*64+bg)*256 + j2];
    hl2[(j2>>4)*36 + (j2&15)*2 + b2] = hpv;
  }
  __syncthreads();
  const float* xgb = xg + (long)(c0&1)*xg_par_str;
  const float* hb = hl2 + ks*36;
  // remote gate base addrs (gate index rotated: r1=(g+1)&3 etc.)
  const int g1 = (g+1)&3, g2c = (g+2)&3, g3 = (g+3)&3;

  for (int sp=0; sp<Sc; sp++){
    const int stepg = c0*Sc + sp;
    const int par = stepg & 1;
    const int target = stepg + 1;
    float x0=0,x1=0,x2=0,x3=0;
    if (t < 512){
      const float* xr = xgb + ((long)(d*Sc+sp)*64 + (bp*2+b2))*1024 + j2;
      x0 = xr[0]; x1 = xr[256]; x2 = xr[512]; x3 = xr[768];
    }
    GEMV4x16
    float r0a = rsum16(s0.x), r0b = rsum16(s0.y);
    float r1a = rsum16(s1.x), r1b = rsum16(s1.y);
    float r2a = rsum16(s2.x), r2b = rsum16(s2.y);
    float r3a = rsum16(s3.x), r3b = rsum16(s3.y);
    if (ks < 4){
      float ra = (ks==0)?r0a:(ks==1)?r1a:(ks==2)?r2a:r3a;
      float rb = (ks==0)?r0b:(ks==1)?r1b:(ks==2)?r2b:r3b;
      int j = rg*4 + ks;
      ol[0][j] = ra; ol[1][j] = rb;
      PK pa; pa.s.v = ra; pa.s.tg = target;
      PK pb; pb.s.v = rb; pb.s.tg = target;
      unsigned long long* sb = send + ((((long)(par*64+grp)*4 + g)*2)*256) + j;
      __hip_atomic_store(sb,       pa.u, __ATOMIC_RELAXED, __HIP_MEMORY_SCOPE_AGENT);
      __hip_atomic_store(sb + 256, pb.u, __ATOMIC_RELAXED, __HIP_MEMORY_SCOPE_AGENT);
    }
    __syncthreads();                             // ol visible; hl2 reads done
    if (t < 512){
      const unsigned long long* rbase =
          send + (long)(par*64+grp)*4*2*256 + b2*256 + j2;
      PK u1, u2, u3;
      u1.u = __hip_atomic_load(rbase + (long)g1*512,  __ATOMIC_RELAXED, __HIP_MEMORY_SCOPE_AGENT);
      u2.u = __hip_atomic_load(rbase + (long)g2c*512, __ATOMIC_RELAXED, __HIP_MEMORY_SCOPE_AGENT);
      u3.u = __hip_atomic_load(rbase + (long)g3*512,  __ATOMIC_RELAXED, __HIP_MEMORY_SCOPE_AGENT);
      int cnt = 0;
      while (u1.s.tg < target || u2.s.tg < target || u3.s.tg < target){
        if (u1.s.tg < target) u1.u = __hip_atomic_load(rbase + (long)g1*512,  __ATOMIC_RELAXED, __HIP_MEMORY_SCOPE_AGENT);
        if (u2.s.tg < target) u2.u = __hip_atomic_load(rbase + (long)g2c*512, __ATOMIC_RELAXED, __HIP_MEMORY_SCOPE_AGENT);
        if (u3.s.tg < target) u3.u = __hip_atomic_load(rbase + (long)g3*512,  __ATOMIC_RELAXED, __HIP_MEMORY_SCOPE_AGENT);
        if (++cnt > (1<<15)) break;
      }
      float vo = ol[b2][j2];
      float a0,a1,a2,a3;                         // gates 0..3 (uniform branch on g)
      if      (g==0){ a0=vo;     a1=u1.s.v; a2=u2.s.v; a3=u3.s.v; }
      else if (g==1){ a1=vo;     a2=u1.s.v; a3=u2.s.v; a0=u3.s.v; }
      else if (g==2){ a2=vo;     a3=u1.s.v; a0=u2.s.v; a1=u3.s.v; }
      else          { a3=vo;     a0=u1.s.v; a1=u2.s.v; a2=u3.s.v; }
      float pi = a0 + x0, pf = a1 + x1, pg = a2 + x2, po = a3 + x3;
      float ii = 1.f/(1.f+expf(-pi)), ff = 1.f/(1.f+expf(-pf));
      float gv = tanhf(pg),           oo = 1.f/(1.f+expf(-po));
      float cn = ff*cst + ii*gv;
      float hn = oo*tanhf(cn);
      if (ml[b2*Sc+sp] != 0){ cst = cn; hpv = hn; }   // freeze on masked steps
      hl2[(j2>>4)*36 + (j2&15)*2 + b2] = hpv;
      if (g == 0){
        int sg = d ? (SLEN-1-stepg) : stepg;
        hs[((long)sg*64 + (bp*2+b2))*512 + d*256 + j2] = hpv;
      }
    }
    __syncthreads();                             // hl2 ready for next gemv
  }
  if (t < 512){
    int bg = bp*2 + b2;
    st_h[(d*64+bg)*256 + j2] = hpv;
    st_c[(d*64+bg)*256 + j2] = cst;
  }
}

__global__ __launch_bounds__(576) void feats_k(
    const float* __restrict__ hs, const float* __restrict__ wout,
    float* __restrict__ feats)
{
  __shared__ __align__(16) float hlds[64*512];
  __shared__ __align__(16) float wl[NTAG*512];
  const int s = blockIdx.x, t = threadIdx.x;
  for (int i = t; i < 64*512/4; i += 576)
    ((f32x4*)hlds)[i] = ((const f32x4*)(hs + (long)s*64*512))[i];
  for (int i = t; i < NTAG*512/4; i += 576)
    ((f32x4*)wl)[i] = ((const f32x4*)wout)[i];
  __syncthreads();
  int b = t / 9, tag = t - b*9;
  float acc = 0.f;
  const float* hb = hlds + b*512;
  const float* wb = wl + tag*512;
  for (int k=0; k<512; k+=4){
    f32x4 h4 = *(const f32x4*)(hb+k);
    f32x4 w4 = *(const f32x4*)(wb+k);
    acc += h4.x*w4.x + h4.y*w4.y + h4.z*w4.z + h4.w*w4.w;
  }
  feats[((long)s*64 + b)*9 + tag] = acc;
}

__global__ __launch_bounds__(64) void viterbi_k(
    const int* __restrict__ ids, const float* __restrict__ feats,
    const float* __restrict__ bout, const float* __restrict__ trans,
    int* __restrict__ outp)
{
  __shared__ float fl[SLEN*NTAG + 64];
  __shared__ unsigned char bps[SLEN*NTAG];
  __shared__ unsigned char mk[SLEN];
  const int b = blockIdx.x, lane = threadIdx.x;
  for (int i=lane; i<SLEN; i+=64) mk[i] = (ids[b*SLEN+i] != 0) ? 1 : 0;
  for (int i=lane; i<SLEN*NTAG; i+=64){
    int s = i/9; int t = i - s*9;
    fl[i] = feats[((long)s*64+b)*9 + t] + bout[t];
  }
  fl[SLEN*NTAG + lane] = 0.f;
  __syncthreads();

  float Tc[9], v[9], vown;
  #pragma unroll
  for (int i=0;i<9;i++) Tc[i] = (lane<9)? trans[i*9 + lane] : 0.f;
  #pragma unroll
  for (int i=0;i<9;i++) v[i] = (i==0)?0.f:NEGV;
  vown = (lane==0)?0.f:NEGV;

  for (int s=0;s<SLEN;s++){
    float best = v[0] + Tc[0]; int bi = 0;
    #pragma unroll
    for (int i=1;i<9;i++){
      float sc = v[i] + Tc[i];
      if (sc > best){ best = sc; bi = i; }       // first-max tie-break
    }
    float nv = best + fl[s*9 + lane];
    bool m = mk[s] != 0;
    if (m && lane<9) vown = nv;
    if (lane < 9) bps[s*9+lane] = (unsigned char)bi;
    #pragma unroll
    for (int i=0;i<9;i++) v[i] = __shfl(vown, i);
  }
  if (lane == 0){
    float best = v[0]; int tag = 0;
    #pragma unroll
    for (int i=1;i<9;i++) if (v[i] > best){ best=v[i]; tag=i; }
    outp[b*SLEN + SLEN-1] = tag;
    for (int t=SLEN-1; t>=1; t--){
      int pv = bps[t*9 + tag];
      if (!mk[t]) pv = 0;
      outp[b*SLEN + t-1] = pv;
      tag = pv;
    }
  }
}

extern "C" void kernel_launch(void* const* d_in, const int* in_sizes, int n_in,
                              void* d_out, int out_size, void* d_ws, size_t ws_size,
                              hipStream_t stream){
  (void)in_sizes; (void)n_in; (void)out_size;
  const int*   ids   = (const int*)  d_in[0];
  const float* embed = (const float*)d_in[2];
  const float* Wih_f = (const float*)d_in[3];
  const float* Whh_f = (const float*)d_in[4];
  const float* b_f   = (const float*)d_in[5];
  const float* Wih_r = (const float*)d_in[6];
  const float* Whh_r = (const float*)d_in[7];
  const float* b_r   = (const float*)d_in[8];
  const float* Wout  = (const float*)d_in[9];
  const float* bout  = (const float*)d_in[10];
  const float* trans = (const float*)d_in[11];

  float* fw = (float*)d_ws;
  size_t off = 0;
  float* wS    = fw + off; off += 1048576;     // 4 MB swizzled Wih+Whh
  unsigned long long* send = (unsigned long long*)(fw + off); off += 524288; // 2 MB tagged
  float* st_h  = fw + off; off += 32768;
  float* st_c  = fw + off; off += 32768;
  float* hs    = fw + off; off += 16777216;    // 64 MB [512][64][512]
  float* featb = fw + off; off += 294912;      // [512][64][9]
  float* xg    = fw + off;
  size_t fixedB = off*4;

  const int cands[7] = {512,256,128,64,32,16,8};
  int Sc = 8;
  for (int ci=0; ci<7; ci++){
    size_t need = fixedB + (size_t)cands[ci]*262144*4;  // xg = 2par*2d*Sc*64*1024 f32
    if (need <= ws_size){ Sc = cands[ci]; break; }
  }
  const long xg_par_str = (long)Sc*131072;
  const int C = SLEN / Sc;

  hipMemsetAsync(send, 0, 524288*4, stream);   // tags must not survive replays
  hipMemsetAsync(st_h, 0, 2*32768*4, stream);  // st_h + st_c contiguous
  prep_k<<<1024,256,0,stream>>>(Wih_f, Whh_f, Wih_r, Whh_r, wS);
  for (int c0=0; c0<C; c0++){
    xproj_k<<<256,1024,0,stream>>>(c0, Sc, ids, embed, wS, b_f, b_r, xg, xg_par_str);
    recur_k<<<256,1024,0,stream>>>(c0, Sc, ids, wS, xg, xg_par_str, hs, st_h, st_c, send);
  }
  feats_k<<<512,576,0,stream>>>(hs, Wout, featb);
  viterbi_k<<<64,64,0,stream>>>(ids, featb, bout, trans, (int*)d_out);
}

// Round 9
// 1988.852 us; speedup vs baseline: 2.3606x; 1.0105x over previous
//
#include <hip/hip_runtime.h>

// BiLSTM-CRF, f32-faithful.
// R9: asm-pin the per-thread weights. R8 counters (VGPR_Count=56) proved the
// allocator NEVER keeps the 64 weight f32s live — it reloads them from L2
// every step (16x global_load_dwordx4/thread/step ~= 1.9us/step, the whole
// per-step budget). A volatile asm identity over the 32 named f32x2 makes
// rematerialization illegal: the values must stay in VGPRs (budget ~110<128
// under waves_per_eu(4,4)) or visibly spill. Everything else identical to R8
// (tagged-data sync, coalesced sends, gate-split, redundant h/c update).

#define SLEN 512
#define NTAG 9
#define NEGV -10000.0f

typedef float f32x2 __attribute__((ext_vector_type(2)));
typedef float f32x4 __attribute__((ext_vector_type(4)));

__device__ __forceinline__ float qsum(float v){
  int t = __builtin_amdgcn_update_dpp(0, __float_as_int(v), 0xB1, 0xF, 0xF, false); // [1,0,3,2]
  v += __int_as_float(t);
  t = __builtin_amdgcn_update_dpp(0, __float_as_int(v), 0x4E, 0xF, 0xF, false);     // [2,3,0,1]
  return v + __int_as_float(t);
}
__device__ __forceinline__ float rsum16(float v){
  v = qsum(v);
  int t = __builtin_amdgcn_update_dpp(0, __float_as_int(v), 0x124, 0xF, 0xF, false); // row_ror:4
  v += __int_as_float(t);
  t = __builtin_amdgcn_update_dpp(0, __float_as_int(v), 0x128, 0xF, 0xF, false);     // row_ror:8
  return v + __int_as_float(t);
}

// dual-batch packed FMA: S.lo += W.lo*h[k0,b0]; S.hi += W.lo*h[k0,b1];
//                        S.lo += W.hi*h[k1,b0]; S.hi += W.hi*h[k1,b1]
#define MAC2(S, WP, HV) { \
  f32x2 _h01{(HV).x,(HV).y}, _h23{(HV).z,(HV).w}; \
  asm("v_pk_fma_f32 %0, %1, %2, %0 op_sel:[0,0,0] op_sel_hi:[0,1,1]" : "+v"(S) : "v"(WP), "v"(_h01)); \
  asm("v_pk_fma_f32 %0, %1, %2, %0 op_sel:[1,0,0] op_sel_hi:[1,1,1]" : "+v"(S) : "v"(WP), "v"(_h23)); }

// load one wS f32x4 into two named weight pairs
#define LDW(rr,kq,A,B) { f32x4 v = wp[((rr)*4+(kq))*1024 + t]; A = f32x2{v.x,v.y}; B = f32x2{v.z,v.w}; }

#define DECLW \
  f32x2 w00,w01,w02,w03,w04,w05,w06,w07; \
  f32x2 w10,w11,w12,w13,w14,w15,w16,w17; \
  f32x2 w20,w21,w22,w23,w24,w25,w26,w27; \
  f32x2 w30,w31,w32,w33,w34,w35,w36,w37; \
  LDW(0,0,w00,w01) LDW(0,1,w02,w03) LDW(0,2,w04,w05) LDW(0,3,w06,w07) \
  LDW(1,0,w10,w11) LDW(1,1,w12,w13) LDW(1,2,w14,w15) LDW(1,3,w16,w17) \
  LDW(2,0,w20,w21) LDW(2,1,w22,w23) LDW(2,2,w24,w25) LDW(2,3,w26,w27) \
  LDW(3,0,w30,w31) LDW(3,1,w32,w33) LDW(3,2,w34,w35) LDW(3,3,w36,w37)

// R9: volatile-asm identity — values become asm-defined, remat from memory
// is illegal, so they must live in VGPRs across the whole step loop.
#define PINW \
  asm volatile("" : "+v"(w00),"+v"(w01),"+v"(w02),"+v"(w03),"+v"(w04),"+v"(w05),"+v"(w06),"+v"(w07)); \
  asm volatile("" : "+v"(w10),"+v"(w11),"+v"(w12),"+v"(w13),"+v"(w14),"+v"(w15),"+v"(w16),"+v"(w17)); \
  asm volatile("" : "+v"(w20),"+v"(w21),"+v"(w22),"+v"(w23),"+v"(w24),"+v"(w25),"+v"(w26),"+v"(w27)); \
  asm volatile("" : "+v"(w30),"+v"(w31),"+v"(w32),"+v"(w33),"+v"(w34),"+v"(w35),"+v"(w36),"+v"(w37));

// chunked gemv: 2 LDS loads + 8 MAC2 per chunk keeps live h-regs at 8
#define GCHUNK(c, WA0,WA1, WB0,WB1, WC0,WC1, WD0,WD1) { \
  f32x4 hA = *(const f32x4*)(hb + (c)*8); \
  f32x4 hB = *(const f32x4*)(hb + (c)*8 + 4); \
  MAC2(s0,WA0,hA) MAC2(s0,WA1,hB) \
  MAC2(s1,WB0,hA) MAC2(s1,WB1,hB) \
  MAC2(s2,WC0,hA) MAC2(s2,WC1,hB) \
  MAC2(s3,WD0,hA) MAC2(s3,WD1,hB) }

#define GEMV4x16 \
  f32x2 s0{0.f,0.f}, s1{0.f,0.f}, s2{0.f,0.f}, s3{0.f,0.f}; \
  GCHUNK(0, w00,w01, w10,w11, w20,w21, w30,w31) \
  GCHUNK(1, w02,w03, w12,w13, w22,w23, w32,w33) \
  GCHUNK(2, w04,w05, w14,w15, w24,w25, w34,w35) \
  GCHUNK(3, w06,w07, w16,w17, w26,w27, w36,w37)

union PK { struct { float v; int tg; } s; unsigned long long u; };

// wS[(((role*2+d)*4+g)*16 + rr*4+kq)*4096 + t*4 + e] =
//   W[g*256 + (t>>4)*4 + rr][(t&15)*16 + kq*4 + e]   role0=Wih, role1=Whh
__global__ void prep_k(const float* __restrict__ wihf, const float* __restrict__ whhf,
                       const float* __restrict__ wihr, const float* __restrict__ whhr,
                       float* __restrict__ wS){
  for (int i = blockIdx.x*blockDim.x + threadIdx.x; i < (1<<20); i += gridDim.x*blockDim.x){
    int e=i&3, t=(i>>2)&1023, inst=(i>>12)&15, g=(i>>16)&3, d=(i>>18)&1, role=(i>>19)&1;
    int rr = inst>>2, kq = inst&3;
    int row = g*256 + (t>>4)*4 + rr;
    int k   = (t&15)*16 + kq*4 + e;
    const float* s = role ? (d? whhr : whhf) : (d? wihr : wihf);
    wS[i] = s[row*256 + k];
  }
}

// xproj: block (d,g,bp): gate-g pre-activations (+bias) for batches
// {2bp,2bp+1}, Sc steps. Thread (rg=t>>4, ks=t&15): rows rg*4..+3, k ks*16..+15.
__global__ __launch_bounds__(1024)
__attribute__((amdgpu_waves_per_eu(4,4)))
void xproj_k(
    int c0, int Sc,
    const int* __restrict__ ids, const float* __restrict__ embed,
    const float* __restrict__ wS,
    const float* __restrict__ bias_f, const float* __restrict__ bias_r,
    float* __restrict__ xg, long xg_par_str)
{
  __shared__ __align__(16) float xl2[2][576];
  __shared__ int ids_l[1024];
  const int t = threadIdx.x;
  const int bid = blockIdx.x;
  const int bp = bid & 31, g = (bid>>5)&3, d = bid>>7;
  const int rg = t>>4, ks = t&15;

  const f32x4* wp = (const f32x4*)(wS + (long)((d*4+g)*16)*4096);
  DECLW
  PINW
  const float bbr = (d ? bias_r : bias_f)[g*256 + rg*4 + (ks&3)];

  for (int i=t; i<2*Sc; i+=1024){
    int b = (i>=Sc) ? 1 : 0, sp = i - b*Sc;
    int sg = d ? (SLEN-1-(c0*Sc+sp)) : (c0*Sc+sp);
    ids_l[i] = ids[(bp*2+b)*SLEN + sg];
  }
  __syncthreads();
  const int bl = t&1, kk = t>>1;                 // loader mapping (t<128)
  if (t < 128){
    f32x4 v = ((const f32x4*)embed)[(long)ids_l[bl*Sc]*64 + kk];
    #pragma unroll
    for (int ii=0; ii<4; ii++){
      int k = kk*4+ii;
      xl2[0][(k>>4)*36 + (k&15)*2 + bl] = v[ii];
    }
  }
  __syncthreads();
  float* xgb = xg + (long)(c0&1)*xg_par_str;
  const float* hb = xl2[0] + ks*36;
  for (int sp=0; sp<Sc; sp++){
    f32x4 pfv;
    const bool hpf = (sp+1 < Sc) && (t < 128);
    if (hpf) pfv = ((const f32x4*)embed)[(long)ids_l[bl*Sc + sp+1]*64 + kk];
    hb = xl2[sp&1] + ks*36;
    GEMV4x16
    float r0a = rsum16(s0.x), r0b = rsum16(s0.y);
    float r1a = rsum16(s1.x), r1b = rsum16(s1.y);
    float r2a = rsum16(s2.x), r2b = rsum16(s2.y);
    float r3a = rsum16(s3.x), r3b = rsum16(s3.y);
    if (ks < 4){
      float ra = (ks==0)?r0a:(ks==1)?r1a:(ks==2)?r2a:r3a;
      float rb = (ks==0)?r0b:(ks==1)?r1b:(ks==2)?r2b:r3b;
      int j = rg*4 + ks;
      long base = ((long)(d*Sc+sp)*64 + bp*2)*1024 + g*256 + j;
      xgb[base]        = ra + bbr;
      xgb[base + 1024] = rb + bbr;
    }
    if (hpf){
      #pragma unroll
      for (int ii=0; ii<4; ii++){
        int k = kk*4+ii;
        xl2[(sp+1)&1][(k>>4)*36 + (k&15)*2 + bl] = pfv[ii];
      }
    }
    __syncthreads();
  }
}

// recur: blockIdx bits [2:0]=grp_lo, [4:3]=g, [7:5]=grp_hi.
// Tagged-data sync: send[par][grp][g][b][j] = {f32 val, i32 tag} (8B atomic).
__global__ __launch_bounds__(1024)
__attribute__((amdgpu_waves_per_eu(4,4)))
void recur_k(
    int c0, int Sc,
    const int* __restrict__ ids,
    const float* __restrict__ wS,
    const float* __restrict__ xg, long xg_par_str,
    float* __restrict__ hs,
    float* __restrict__ st_h, float* __restrict__ st_c,
    unsigned long long* __restrict__ send)
{
  __shared__ __align__(16) float hl2[576];
  __shared__ float ol[2][256];
  __shared__ int ml[1024];
  const int t = threadIdx.x;
  const int bid = blockIdx.x;
  const int g = (bid>>3)&3;
  const int grp = (bid&7) | ((bid>>5)<<3);
  const int d = grp>>5, bp = grp&31;
  const int rg = t>>4, ks = t&15;

  const f32x4* wp = (const f32x4*)(wS + (long)(((2+d)*4+g)*16)*4096);
  DECLW
  PINW

  for (int i=t; i<2*Sc; i+=1024){
    int b = (i>=Sc) ? 1 : 0, sp = i - b*Sc;
    int sg = d ? (SLEN-1-(c0*Sc+sp)) : (c0*Sc+sp);
    ml[i] = ids[(bp*2+b)*SLEN + sg];
  }
  float cst = 0.f, hpv = 0.f;
  const int j2 = t&255, b2 = t>>8;               // update mapping (t<512)
  if (t < 512){
    int bg = bp*2 + b2;
    hpv = st_h[(d*64+bg)*256 + j2];
    cst = st_c[(d*64+bg)*256 + j2];
    hl2[(j2>>4)*36 + (j2&15)*2 + b2] = hpv;
  }
  __syncthreads();
  const float* xgb = xg + (long)(c0&1)*xg_par_str;
  const float* hb = hl2 + ks*36;
  const int g1 = (g+1)&3, g2c = (g+2)&3, g3 = (g+3)&3;

  for (int sp=0; sp<Sc; sp++){
    const int stepg = c0*Sc + sp;
    const int par = stepg & 1;
    const int target = stepg + 1;
    float x0=0,x1=0,x2=0,x3=0;
    if (t < 512){
      const float* xr = xgb + ((long)(d*Sc+sp)*64 + (bp*2+b2))*1024 + j2;
      x0 = xr[0]; x1 = xr[256]; x2 = xr[512]; x3 = xr[768];
    }
    GEMV4x16
    float r0a = rsum16(s0.x), r0b = rsum16(s0.y);
    float r1a = rsum16(s1.x), r1b = rsum16(s1.y);
    float r2a = rsum16(s2.x), r2b = rsum16(s2.y);
    float r3a = rsum16(s3.x), r3b = rsum16(s3.y);
    if (ks < 4){
      float ra = (ks==0)?r0a:(ks==1)?r1a:(ks==2)?r2a:r3a;
      float rb = (ks==0)?r0b:(ks==1)?r1b:(ks==2)?r2b:r3b;
      int j = rg*4 + ks;
      ol[0][j] = ra; ol[1][j] = rb;
      PK pa; pa.s.v = ra; pa.s.tg = target;
      PK pb; pb.s.v = rb; pb.s.tg = target;
      unsigned long long* sb = send + ((((long)(par*64+grp)*4 + g)*2)*256) + j;
      __hip_atomic_store(sb,       pa.u, __ATOMIC_RELAXED, __HIP_MEMORY_SCOPE_AGENT);
      __hip_atomic_store(sb + 256, pb.u, __ATOMIC_RELAXED, __HIP_MEMORY_SCOPE_AGENT);
    }
    __syncthreads();                             // ol visible; hl2 reads done
    if (t < 512){
      const unsigned long long* rbase =
          send + (long)(par*64+grp)*4*2*256 + b2*256 + j2;
      PK u1, u2, u3;
      u1.u = __hip_atomic_load(rbase + (long)g1*512,  __ATOMIC_RELAXED, __HIP_MEMORY_SCOPE_AGENT);
      u2.u = __hip_atomic_load(rbase + (long)g2c*512, __ATOMIC_RELAXED, __HIP_MEMORY_SCOPE_AGENT);
      u3.u = __hip_atomic_load(rbase + (long)g3*512,  __ATOMIC_RELAXED, __HIP_MEMORY_SCOPE_AGENT);
      int cnt = 0;
      while (u1.s.tg < target || u2.s.tg < target || u3.s.tg < target){
        if (u1.s.tg < target) u1.u = __hip_atomic_load(rbase + (long)g1*512,  __ATOMIC_RELAXED, __HIP_MEMORY_SCOPE_AGENT);
        if (u2.s.tg < target) u2.u = __hip_atomic_load(rbase + (long)g2c*512, __ATOMIC_RELAXED, __HIP_MEMORY_SCOPE_AGENT);
        if (u3.s.tg < target) u3.u = __hip_atomic_load(rbase + (long)g3*512,  __ATOMIC_RELAXED, __HIP_MEMORY_SCOPE_AGENT);
        if (++cnt > (1<<15)) break;
      }
      float vo = ol[b2][j2];
      float a0,a1,a2,a3;                         // gates 0..3 (uniform branch on g)
      if      (g==0){ a0=vo;     a1=u1.s.v; a2=u2.s.v; a3=u3.s.v; }
      else if (g==1){ a1=vo;     a2=u1.s.v; a3=u2.s.v; a0=u3.s.v; }
      else if (g==2){ a2=vo;     a3=u1.s.v; a0=u2.s.v; a1=u3.s.v; }
      else          { a3=vo;     a0=u1.s.v; a1=u2.s.v; a2=u3.s.v; }
      float pi = a0 + x0, pf = a1 + x1, pg = a2 + x2, po = a3 + x3;
      float ii = 1.f/(1.f+expf(-pi)), ff = 1.f/(1.f+expf(-pf));
      float gv = tanhf(pg),           oo = 1.f/(1.f+expf(-po));
      float cn = ff*cst + ii*gv;
      float hn = oo*tanhf(cn);
      if (ml[b2*Sc+sp] != 0){ cst = cn; hpv = hn; }   // freeze on masked steps
      hl2[(j2>>4)*36 + (j2&15)*2 + b2] = hpv;
      if (g == 0){
        int sg = d ? (SLEN-1-stepg) : stepg;
        hs[((long)sg*64 + (bp*2+b2))*512 + d*256 + j2] = hpv;
      }
    }
    __syncthreads();                             // hl2 ready for next gemv
  }
  if (t < 512){
    int bg = bp*2 + b2;
    st_h[(d*64+bg)*256 + j2] = hpv;
    st_c[(d*64+bg)*256 + j2] = cst;
  }
}

__global__ __launch_bounds__(576) void feats_k(
    const float* __restrict__ hs, const float* __restrict__ wout,
    float* __restrict__ feats)
{
  __shared__ __align__(16) float hlds[64*512];
  __shared__ __align__(16) float wl[NTAG*512];
  const int s = blockIdx.x, t = threadIdx.x;
  for (int i = t; i < 64*512/4; i += 576)
    ((f32x4*)hlds)[i] = ((const f32x4*)(hs + (long)s*64*512))[i];
  for (int i = t; i < NTAG*512/4; i += 576)
    ((f32x4*)wl)[i] = ((const f32x4*)wout)[i];
  __syncthreads();
  int b = t / 9, tag = t - b*9;
  float acc = 0.f;
  const float* hb = hlds + b*512;
  const float* wb = wl + tag*512;
  for (int k=0; k<512; k+=4){
    f32x4 h4 = *(const f32x4*)(hb+k);
    f32x4 w4 = *(const f32x4*)(wb+k);
    acc += h4.x*w4.x + h4.y*w4.y + h4.z*w4.z + h4.w*w4.w;
  }
  feats[((long)s*64 + b)*9 + tag] = acc;
}

__global__ __launch_bounds__(64) void viterbi_k(
    const int* __restrict__ ids, const float* __restrict__ feats,
    const float* __restrict__ bout, const float* __restrict__ trans,
    int* __restrict__ outp)
{
  __shared__ float fl[SLEN*NTAG + 64];
  __shared__ unsigned char bps[SLEN*NTAG];
  __shared__ unsigned char mk[SLEN];
  const int b = blockIdx.x, lane = threadIdx.x;
  for (int i=lane; i<SLEN; i+=64) mk[i] = (ids[b*SLEN+i] != 0) ? 1 : 0;
  for (int i=lane; i<SLEN*NTAG; i+=64){
    int s = i/9; int t = i - s*9;
    fl[i] = feats[((long)s*64+b)*9 + t] + bout[t];
  }
  fl[SLEN*NTAG + lane] = 0.f;
  __syncthreads();

  float Tc[9], v[9], vown;
  #pragma unroll
  for (int i=0;i<9;i++) Tc[i] = (lane<9)? trans[i*9 + lane] : 0.f;
  #pragma unroll
  for (int i=0;i<9;i++) v[i] = (i==0)?0.f:NEGV;
  vown = (lane==0)?0.f:NEGV;

  for (int s=0;s<SLEN;s++){
    float best = v[0] + Tc[0]; int bi = 0;
    #pragma unroll
    for (int i=1;i<9;i++){
      float sc = v[i] + Tc[i];
      if (sc > best){ best = sc; bi = i; }       // first-max tie-break
    }
    float nv = best + fl[s*9 + lane];
    bool m = mk[s] != 0;
    if (m && lane<9) vown = nv;
    if (lane < 9) bps[s*9+lane] = (unsigned char)bi;
    #pragma unroll
    for (int i=0;i<9;i++) v[i] = __shfl(vown, i);
  }
  if (lane == 0){
    float best = v[0]; int tag = 0;
    #pragma unroll
    for (int i=1;i<9;i++) if (v[i] > best){ best=v[i]; tag=i; }
    outp[b*SLEN + SLEN-1] = tag;
    for (int t=SLEN-1; t>=1; t--){
      int pv = bps[t*9 + tag];
      if (!mk[t]) pv = 0;
      outp[b*SLEN + t-1] = pv;
      tag = pv;
    }
  }
}

extern "C" void kernel_launch(void* const* d_in, const int* in_sizes, int n_in,
                              void* d_out, int out_size, void* d_ws, size_t ws_size,
                              hipStream_t stream){
  (void)in_sizes; (void)n_in; (void)out_size;
  const int*   ids   = (const int*)  d_in[0];
  const float* embed = (const float*)d_in[2];
  const float* Wih_f = (const float*)d_in[3];
  const float* Whh_f = (const float*)d_in[4];
  const float* b_f   = (const float*)d_in[5];
  const float* Wih_r = (const float*)d_in[6];
  const float* Whh_r = (const float*)d_in[7];
  const float* b_r   = (const float*)d_in[8];
  const float* Wout  = (const float*)d_in[9];
  const float* bout  = (const float*)d_in[10];
  const float* trans = (const float*)d_in[11];

  float* fw = (float*)d_ws;
  size_t off = 0;
  float* wS    = fw + off; off += 1048576;     // 4 MB swizzled Wih+Whh
  unsigned long long* send = (unsigned long long*)(fw + off); off += 524288; // 2 MB tagged
  float* st_h  = fw + off; off += 32768;
  float* st_c  = fw + off; off += 32768;
  float* hs    = fw + off; off += 16777216;    // 64 MB [512][64][512]
  float* featb = fw + off; off += 294912;      // [512][64][9]
  float* xg    = fw + off;
  size_t fixedB = off*4;

  const int cands[7] = {512,256,128,64,32,16,8};
  int Sc = 8;
  for (int ci=0; ci<7; ci++){
    size_t need = fixedB + (size_t)cands[ci]*262144*4;  // xg = 2par*2d*Sc*64*1024 f32
    if (need <= ws_size){ Sc = cands[ci]; break; }
  }
  const long xg_par_str = (long)Sc*131072;
  const int C = SLEN / Sc;

  hipMemsetAsync(send, 0, 524288*4, stream);   // tags must not survive replays
  hipMemsetAsync(st_h, 0, 2*32768*4, stream);  // st_h + st_c contiguous
  prep_k<<<1024,256,0,stream>>>(Wih_f, Whh_f, Wih_r, Whh_r, wS);
  for (int c0=0; c0<C; c0++){
    xproj_k<<<256,1024,0,stream>>>(c0, Sc, ids, embed, wS, b_f, b_r, xg, xg_par_str);
    recur_k<<<256,1024,0,stream>>>(c0, Sc, ids, wS, xg, xg_par_str, hs, st_h, st_c, send);
  }
  feats_k<<<512,576,0,stream>>>(hs, Wout, featb);
  viterbi_k<<<64,64,0,stream>>>(ids, featb, bout, trans, (int*)d_out);
}